// Round 1
// baseline (481.646 us; speedup 1.0000x reference)
//
#include <hip/hip_runtime.h>
#include <stdint.h>

#define MDIM 8192
#define KDIM 4096
#define NDIM 4096

typedef int v4i __attribute__((ext_vector_type(4)));

// ---------------- absmax (per-tensor), x and w in ONE launch ----------------
// blocks [0,1024) -> x (8M float4, 8 iters of 4), [1024,1536) -> w (4M float4, 8 iters of 4)
__global__ __launch_bounds__(256) void absmax2_kernel(const float* __restrict__ x,
                                                      const float* __restrict__ w,
                                                      unsigned* __restrict__ bits) {
    __shared__ float smax[4];
    const float4* src;
    int idx, stride, n4;
    unsigned* slot;
    if (blockIdx.x < 1024) {
        src = (const float4*)x;
        idx = blockIdx.x * 256 + threadIdx.x;
        stride = 1024 * 256;
        n4 = MDIM * KDIM / 4;
        slot = bits;
    } else {
        src = (const float4*)w;
        idx = (blockIdx.x - 1024) * 256 + threadIdx.x;
        stride = 512 * 256;
        n4 = NDIM * KDIM / 4;
        slot = bits + 1;
    }
    float m = 0.0f;
    for (int i = idx; i < n4; i += 4 * stride) {
        float4 a = src[i];
        float4 b = src[i + stride];
        float4 c = src[i + 2 * stride];
        float4 d = src[i + 3 * stride];
        m = fmaxf(m, fmaxf(fmaxf(fabsf(a.x), fabsf(a.y)), fmaxf(fabsf(a.z), fabsf(a.w))));
        m = fmaxf(m, fmaxf(fmaxf(fabsf(b.x), fabsf(b.y)), fmaxf(fabsf(b.z), fabsf(b.w))));
        m = fmaxf(m, fmaxf(fmaxf(fabsf(c.x), fabsf(c.y)), fmaxf(fabsf(c.z), fabsf(c.w))));
        m = fmaxf(m, fmaxf(fmaxf(fabsf(d.x), fabsf(d.y)), fmaxf(fabsf(d.z), fabsf(d.w))));
    }
#pragma unroll
    for (int off = 32; off > 0; off >>= 1)
        m = fmaxf(m, __shfl_down(m, off, 64));
    if ((threadIdx.x & 63) == 0) smax[threadIdx.x >> 6] = m;
    __syncthreads();
    if (threadIdx.x == 0) {
        float bm = fmaxf(fmaxf(smax[0], smax[1]), fmaxf(smax[2], smax[3]));
        atomicMax(slot, __float_as_uint(bm));  // |x| >= 0: uint order == float order
    }
}

// ---------------- quantize fp32 -> int8, x and w in ONE launch ----------------
// blocks [0,2048) -> x (4 iters of 4), [2048,3072) -> w (4 iters of 4)
__global__ __launch_bounds__(256) void quant2_kernel(const float* __restrict__ x,
                                                     const float* __restrict__ w,
                                                     const unsigned* __restrict__ bits,
                                                     int* __restrict__ xq,
                                                     int* __restrict__ wq) {
    const float4* src;
    int idx, stride, n4;
    int* dst;
    float amax;
    if (blockIdx.x < 2048) {
        src = (const float4*)x;
        idx = blockIdx.x * 256 + threadIdx.x;
        stride = 2048 * 256;
        n4 = MDIM * KDIM / 4;
        dst = xq;
        amax = __uint_as_float(bits[0]);
    } else {
        src = (const float4*)w;
        idx = (blockIdx.x - 2048) * 256 + threadIdx.x;
        stride = 1024 * 256;
        n4 = NDIM * KDIM / 4;
        dst = wq;
        amax = __uint_as_float(bits[1]);
    }
    const float scale = (amax > 0.0f) ? (amax / 127.0f) : 1.0f;
    for (int i = idx; i < n4; i += 4 * stride) {
        float4 v[4];
        v[0] = src[i];
        v[1] = src[i + stride];
        v[2] = src[i + 2 * stride];
        v[3] = src[i + 3 * stride];
#pragma unroll
        for (int u = 0; u < 4; ++u) {
            int a = __float2int_rn(v[u].x / scale);  // IEEE div + rn == jnp.round(t/scale)
            int b = __float2int_rn(v[u].y / scale);
            int c = __float2int_rn(v[u].z / scale);
            int d = __float2int_rn(v[u].w / scale);
            a = min(127, max(-127, a));
            b = min(127, max(-127, b));
            c = min(127, max(-127, c));
            d = min(127, max(-127, d));
            dst[i + u * stride] =
                (a & 0xFF) | ((b & 0xFF) << 8) | ((c & 0xFF) << 16) | ((d & 0xFF) << 24);
        }
    }
}

// ---------------- int8 GEMM: C = Aq[M,K] . Wq[N,K]^T, dequant + bias ----------------
// 256x256 tile, BK=128 bytes, 8 waves (2M x 4N), per-wave 128x64 out.
// 4 phases per K-tile: {ds_read subtile; setprio(1); 16 MFMA; setprio(0); s_barrier}.
// All 8 global_load_lds for tile t+1 issued at phase 1 of tile t; single vmcnt(0)
// drain at phase 4 (loads get ~3 phases of MFMA to complete).
// LDS granule swizzle g ^= (row&7) applied on BOTH stage-source and ds_read (rule 21).
__global__ __launch_bounds__(512, 2) void gemm_i8(
    const signed char* __restrict__ Aq,
    const signed char* __restrict__ Wq,
    const float* __restrict__ bias,
    const unsigned* __restrict__ bits,
    float* __restrict__ out) {
    // [2 bufs][256 rows][128 bytes] each for A and B = 128 KB total (1 block/CU)
    __shared__ __align__(16) signed char As[2 * 32768];
    __shared__ __align__(16) signed char Bs[2 * 32768];

    const int tid  = threadIdx.x;
    const int lane = tid & 63;
    const int wave = tid >> 6;
    const int wm = wave >> 2;   // 0..1 -> M half (128 rows)
    const int wn = wave & 3;    // 0..3 -> N quarter (64 cols)
    const int l15 = lane & 15;
    const int l4  = lane >> 4;  // 0..3
    const int swz = l15 & 7;    // read-side swizzle = row&7

    const int m0 = blockIdx.y * 256;
    const int n0 = blockIdx.x * 256;

    // staging: thread (u, tid) -> LDS linear granule (row = u*64 + tid>>3, g = tid&7);
    // source granule pre-swizzled: g ^ (row&7)
    const int srow = tid >> 3;                         // 0..63
    const int scol = ((tid & 7) ^ (srow & 7)) << 4;    // pre-swizzled source byte col
    const signed char* aSrc[4];
    const signed char* bSrc[4];
#pragma unroll
    for (int u = 0; u < 4; ++u) {
        aSrc[u] = Aq + (size_t)(m0 + u * 64 + srow) * KDIM + scol;
        bSrc[u] = Wq + (size_t)(n0 + u * 64 + srow) * KDIM + scol;
    }
    const int ldsOff = tid * 16;

    v4i acc[8][4] = {};
    v4i af[4][2], bf[2][2];

#define STAGE_FULL(BUF, KB) do {                                                          \
    _Pragma("unroll") for (int u = 0; u < 4; ++u)                                         \
        __builtin_amdgcn_global_load_lds(                                                 \
            (const __attribute__((address_space(1))) void*)(aSrc[u] + (KB)),              \
            (__attribute__((address_space(3))) void*)(As + (BUF)*32768 + u*8192 + ldsOff),\
            16, 0, 0);                                                                    \
    _Pragma("unroll") for (int u = 0; u < 4; ++u)                                         \
        __builtin_amdgcn_global_load_lds(                                                 \
            (const __attribute__((address_space(1))) void*)(bSrc[u] + (KB)),              \
            (__attribute__((address_space(3))) void*)(Bs + (BUF)*32768 + u*8192 + ldsOff),\
            16, 0, 0);                                                                    \
} while (0)

// data for (row, want-granule g) lives at LDS granule g ^ (row&7); row&7 == l15&7 == swz
#define LDA(dst, BUF, i, kk) dst = *(const v4i*)(As + (BUF)*32768 +                       \
        (wm*128 + (i)*16 + l15)*128 + (((((kk)<<2) | l4) ^ swz) << 4))
#define LDB(dst, BUF, j, kk) dst = *(const v4i*)(Bs + (BUF)*32768 +                       \
        (wn*64 + (j)*16 + l15)*128 + (((((kk)<<2) | l4) ^ swz) << 4))

#define MFMA8(I0, J0) do {                                                                \
    _Pragma("unroll") for (int kk = 0; kk < 2; ++kk)                                      \
    _Pragma("unroll") for (int i = 0; i < 4; ++i)                                         \
    _Pragma("unroll") for (int j = 0; j < 2; ++j)                                         \
        acc[(I0)+i][(J0)+j] = __builtin_amdgcn_mfma_i32_16x16x64_i8(                      \
            af[i][kk], bf[j][kk], acc[(I0)+i][(J0)+j], 0, 0, 0);                          \
} while (0)

#define BAR() do { __builtin_amdgcn_s_barrier(); asm volatile("" ::: "memory"); } while (0)

#define TILE(BUF, DO_STAGE, NKB) do {                                                     \
    /* phase 1: issue next-tile staging early, compute quadrant (i0-3, j0-1) */           \
    if (DO_STAGE) STAGE_FULL(1 - (BUF), NKB);                                             \
    _Pragma("unroll") for (int i = 0; i < 4; ++i) { LDA(af[i][0], BUF, i, 0);             \
                                                    LDA(af[i][1], BUF, i, 1); }           \
    _Pragma("unroll") for (int j = 0; j < 2; ++j) { LDB(bf[j][0], BUF, j, 0);             \
                                                    LDB(bf[j][1], BUF, j, 1); }           \
    __builtin_amdgcn_s_setprio(1); MFMA8(0, 0); __builtin_amdgcn_s_setprio(0);            \
    BAR();                                                                                \
    /* phase 2: quadrant (i0-3, j2-3) — af kept live */                                   \
    _Pragma("unroll") for (int j = 0; j < 2; ++j) { LDB(bf[j][0], BUF, 2 + j, 0);         \
                                                    LDB(bf[j][1], BUF, 2 + j, 1); }       \
    __builtin_amdgcn_s_setprio(1); MFMA8(0, 2); __builtin_amdgcn_s_setprio(0);            \
    BAR();                                                                                \
    /* phase 3: quadrant (i4-7, j2-3) — bf kept live */                                   \
    _Pragma("unroll") for (int i = 0; i < 4; ++i) { LDA(af[i][0], BUF, 4 + i, 0);         \
                                                    LDA(af[i][1], BUF, 4 + i, 1); }       \
    __builtin_amdgcn_s_setprio(1); MFMA8(4, 2); __builtin_amdgcn_s_setprio(0);            \
    BAR();                                                                                \
    /* phase 4: quadrant (i4-7, j0-1); drain next-tile loads, swap */                     \
    _Pragma("unroll") for (int j = 0; j < 2; ++j) { LDB(bf[j][0], BUF, j, 0);             \
                                                    LDB(bf[j][1], BUF, j, 1); }           \
    __builtin_amdgcn_s_setprio(1); MFMA8(4, 0); __builtin_amdgcn_s_setprio(0);            \
    asm volatile("s_waitcnt vmcnt(0)" ::: "memory");                                      \
    BAR();                                                                                \
} while (0)

    STAGE_FULL(0, 0);
    asm volatile("s_waitcnt vmcnt(0)" ::: "memory");
    BAR();

#pragma unroll 1
    for (int kb = 0; kb < KDIM; kb += 256) {
        TILE(0, true, kb + 128);
        TILE(1, (kb + 256) < KDIM, kb + 256);
    }

    const float ax = __uint_as_float(bits[0]);
    const float aw = __uint_as_float(bits[1]);
    const float s = (ax / 127.0f) * (aw / 127.0f);

    // C/D layout (16x16): col = lane&15, row = (lane>>4)*4 + reg
#pragma unroll
    for (int j = 0; j < 4; ++j) {
        const int col = n0 + wn * 64 + j * 16 + l15;
        const float bcol = bias[col];
#pragma unroll
        for (int i = 0; i < 8; ++i) {
            const int row0 = m0 + wm * 128 + i * 16 + l4 * 4;
#pragma unroll
            for (int r = 0; r < 4; ++r)
                out[(size_t)(row0 + r) * NDIM + col] = (float)acc[i][j][r] * s + bcol;
        }
    }
#undef STAGE_FULL
#undef LDA
#undef LDB
#undef MFMA8
#undef BAR
#undef TILE
}

extern "C" void kernel_launch(void* const* d_in, const int* in_sizes, int n_in,
                              void* d_out, int out_size, void* d_ws, size_t ws_size,
                              hipStream_t stream) {
    const float* x    = (const float*)d_in[0];
    const float* w    = (const float*)d_in[1];
    const float* bias = (const float*)d_in[2];
    float* out = (float*)d_out;

    unsigned* bits = (unsigned*)d_ws;                 // [0]=absmax(x), [1]=absmax(w)
    signed char* xq = (signed char*)d_ws + 64;        // M*K int8 = 32 MB
    signed char* wq = xq + (size_t)MDIM * KDIM;       // N*K int8 = 16 MB

    hipMemsetAsync(d_ws, 0, 64, stream);

    absmax2_kernel<<<1536, 256, 0, stream>>>(x, w, bits);
    quant2_kernel<<<3072, 256, 0, stream>>>(x, w, bits, (int*)xq, (int*)wq);

    dim3 grid(NDIM / 256, MDIM / 256);
    gemm_i8<<<grid, 512, 0, stream>>>(xq, wq, bias, bits, out);
}

// Round 2
// 454.858 us; speedup vs baseline: 1.0589x; 1.0589x over previous
//
#include <hip/hip_runtime.h>
#include <stdint.h>

#define MDIM 8192
#define KDIM 4096
#define NDIM 4096

typedef int v4i __attribute__((ext_vector_type(4)));

// ---------------- absmax (per-tensor), x and w in ONE launch ----------------
__global__ __launch_bounds__(256) void absmax2_kernel(const float* __restrict__ x,
                                                      const float* __restrict__ w,
                                                      unsigned* __restrict__ bits) {
    __shared__ float smax[4];
    const float4* src;
    int idx, stride, n4;
    unsigned* slot;
    if (blockIdx.x < 1024) {
        src = (const float4*)x;
        idx = blockIdx.x * 256 + threadIdx.x;
        stride = 1024 * 256;
        n4 = MDIM * KDIM / 4;
        slot = bits;
    } else {
        src = (const float4*)w;
        idx = (blockIdx.x - 1024) * 256 + threadIdx.x;
        stride = 512 * 256;
        n4 = NDIM * KDIM / 4;
        slot = bits + 1;
    }
    float m = 0.0f;
    for (int i = idx; i < n4; i += 4 * stride) {
        float4 a = src[i];
        float4 b = src[i + stride];
        float4 c = src[i + 2 * stride];
        float4 d = src[i + 3 * stride];
        m = fmaxf(m, fmaxf(fmaxf(fabsf(a.x), fabsf(a.y)), fmaxf(fabsf(a.z), fabsf(a.w))));
        m = fmaxf(m, fmaxf(fmaxf(fabsf(b.x), fabsf(b.y)), fmaxf(fabsf(b.z), fabsf(b.w))));
        m = fmaxf(m, fmaxf(fmaxf(fabsf(c.x), fabsf(c.y)), fmaxf(fabsf(c.z), fabsf(c.w))));
        m = fmaxf(m, fmaxf(fmaxf(fabsf(d.x), fabsf(d.y)), fmaxf(fabsf(d.z), fabsf(d.w))));
    }
#pragma unroll
    for (int off = 32; off > 0; off >>= 1)
        m = fmaxf(m, __shfl_down(m, off, 64));
    if ((threadIdx.x & 63) == 0) smax[threadIdx.x >> 6] = m;
    __syncthreads();
    if (threadIdx.x == 0) {
        float bm = fmaxf(fmaxf(smax[0], smax[1]), fmaxf(smax[2], smax[3]));
        atomicMax(slot, __float_as_uint(bm));  // |x| >= 0: uint order == float order
    }
}

// ---------------- quantize fp32 -> int8, x and w in ONE launch ----------------
__global__ __launch_bounds__(256) void quant2_kernel(const float* __restrict__ x,
                                                     const float* __restrict__ w,
                                                     const unsigned* __restrict__ bits,
                                                     int* __restrict__ xq,
                                                     int* __restrict__ wq) {
    const float4* src;
    int idx, stride, n4;
    int* dst;
    float amax;
    if (blockIdx.x < 2048) {
        src = (const float4*)x;
        idx = blockIdx.x * 256 + threadIdx.x;
        stride = 2048 * 256;
        n4 = MDIM * KDIM / 4;
        dst = xq;
        amax = __uint_as_float(bits[0]);
    } else {
        src = (const float4*)w;
        idx = (blockIdx.x - 2048) * 256 + threadIdx.x;
        stride = 1024 * 256;
        n4 = NDIM * KDIM / 4;
        dst = wq;
        amax = __uint_as_float(bits[1]);
    }
    const float scale = (amax > 0.0f) ? (amax / 127.0f) : 1.0f;
    for (int i = idx; i < n4; i += 4 * stride) {
        float4 v[4];
        v[0] = src[i];
        v[1] = src[i + stride];
        v[2] = src[i + 2 * stride];
        v[3] = src[i + 3 * stride];
#pragma unroll
        for (int u = 0; u < 4; ++u) {
            int a = __float2int_rn(v[u].x / scale);  // IEEE div + rn == jnp.round(t/scale)
            int b = __float2int_rn(v[u].y / scale);
            int c = __float2int_rn(v[u].z / scale);
            int d = __float2int_rn(v[u].w / scale);
            a = min(127, max(-127, a));
            b = min(127, max(-127, b));
            c = min(127, max(-127, c));
            d = min(127, max(-127, d));
            dst[i + u * stride] =
                (a & 0xFF) | ((b & 0xFF) << 8) | ((c & 0xFF) << 16) | ((d & 0xFF) << 24);
        }
    }
}

// ---------------- int8 GEMM: C = Aq[M,K] . Wq[N,K]^T, dequant + bias ----------------
// m201-style 8-phase counted-vmcnt schedule, mapped to i8 (K-tile = 128 B).
// 256x256 tile, 8 waves (2M x 4N), per-wave 128x64 out, dbuf LDS 128 KB.
// Half-tile staging stream per tile T: H[4T+0]=B-lo, +1=B-hi, +2=A-lo, +3=A-hi
// (each half = 128 rows x 128 B = 2 global_load_lds per thread).
// Stage lead = 7 halves -> 3 halves (6 loads) in flight; vmcnt(6) once per tile
// at q3 forces A-hi(T+1) complete. Ledger (verified):
//   q0 of T stages A-hi(T+1)  [overwrites A-hi(T-1), last read q2 of T-1]
//   q1 of T stages B-lo(T+2)  [overwrites B-lo(T),   last read q0 of T]
//   q2 of T stages B-hi(T+2)  [overwrites B-hi(T),   last read q1 of T]
//   q3 of T stages A-lo(T+2)  [overwrites A-lo(T),   last read q2 of T]
// Every overwrite is issued >=1 barrier after the slot's last ds_read retires.
// Per phase: {ds_reads; stage; barrier; lgkmcnt(0); setprio(1); 16 MFMA; setprio(0); [vmcnt]; barrier}
__global__ __launch_bounds__(512, 2) void gemm_i8(
    const signed char* __restrict__ Aq,
    const signed char* __restrict__ Wq,
    const float* __restrict__ bias,
    const unsigned* __restrict__ bits,
    float* __restrict__ out) {
    __shared__ __align__(16) signed char As[2 * 32768];  // [buf][256 rows][128 B]
    __shared__ __align__(16) signed char Bs[2 * 32768];

    const int tid  = threadIdx.x;
    const int lane = tid & 63;
    const int wave = tid >> 6;
    const int wm = wave >> 2;   // 0..1 -> M half (128 rows)
    const int wn = wave & 3;    // 0..3 -> N quarter (64 cols)
    const int l15 = lane & 15;
    const int l4  = lane >> 4;  // 0..3
    const int swz = l15 & 7;    // read-side swizzle = row&7

    const int m0 = blockIdx.y * 256;
    const int n0 = blockIdx.x * 256;

    // staging: thread t covers granule (row = c*64 + t>>3, g = t&7) of chunk c;
    // source granule pre-swizzled g ^ (row&7) so linear LDS + swizzled read match (rule 21)
    const int srow = tid >> 3;                         // 0..63 within chunk
    const int scol = ((tid & 7) ^ (srow & 7)) << 4;    // pre-swizzled source byte col
    const signed char* aSrc[4];
    const signed char* bSrc[4];
#pragma unroll
    for (int c = 0; c < 4; ++c) {
        aSrc[c] = Aq + (size_t)(m0 + c * 64 + srow) * KDIM + scol;
        bSrc[c] = Wq + (size_t)(n0 + c * 64 + srow) * KDIM + scol;
    }
    const int ldst = tid * 16;

    v4i acc[8][4] = {};
    v4i af[4][2], bf[4][2];

#define GLL(SRC, DST) __builtin_amdgcn_global_load_lds(                                   \
        (const __attribute__((address_space(1))) void*)(SRC),                             \
        (__attribute__((address_space(3))) void*)(DST), 16, 0, 0)

// stage half h (0=lo rows 0-127, 1=hi rows 128-255) at k-byte-offset KO into buffer BUF
#define STG_A(BUF, h, KO) do {                                                            \
    GLL(aSrc[(h)*2 + 0] + (KO), As + (BUF)*32768 + (h)*16384 + 0*8192 + ldst);            \
    GLL(aSrc[(h)*2 + 1] + (KO), As + (BUF)*32768 + (h)*16384 + 1*8192 + ldst);            \
} while (0)
#define STG_B(BUF, h, KO) do {                                                            \
    GLL(bSrc[(h)*2 + 0] + (KO), Bs + (BUF)*32768 + (h)*16384 + 0*8192 + ldst);            \
    GLL(bSrc[(h)*2 + 1] + (KO), Bs + (BUF)*32768 + (h)*16384 + 1*8192 + ldst);            \
} while (0)

// data for (row, k-granule g) lives at LDS granule g ^ (row&7); row&7 == l15&7 == swz
#define LDA(BUF, i, kk) (*(const v4i*)(As + (BUF)*32768 +                                 \
        (wm*128 + (i)*16 + l15)*128 + (((((kk)<<2) | l4) ^ swz) << 4)))
#define LDB(BUF, j, kk) (*(const v4i*)(Bs + (BUF)*32768 +                                 \
        (wn*64 + (j)*16 + l15)*128 + (((((kk)<<2) | l4) ^ swz) << 4)))

#define MQ(I0, J0) do {                                                                   \
    _Pragma("unroll") for (int kk = 0; kk < 2; ++kk)                                      \
    _Pragma("unroll") for (int i = 0; i < 4; ++i)                                         \
    _Pragma("unroll") for (int j = 0; j < 2; ++j)                                         \
        acc[(I0)+i][(J0)+j] = __builtin_amdgcn_mfma_i32_16x16x64_i8(                      \
            af[i][kk], bf[(J0)+j][kk], acc[(I0)+i][(J0)+j], 0, 0, 0);                     \
} while (0)

#define BAR()   do { __builtin_amdgcn_s_barrier(); asm volatile("" ::: "memory"); } while (0)
#define LGKM0() asm volatile("s_waitcnt lgkmcnt(0)" ::: "memory")
#define VMC(n)  asm volatile("s_waitcnt vmcnt(" #n ")" ::: "memory")

// One K-tile (128 B). NBUF = 1-BUF. KO1 = (T+1)*128, KO2 = (T+2)*128.
// ST_Q0 gates the q0 stage (A-hi of T+1); ST_Q123 gates the T+2 stages.
#define TILE_BODY(BUF, NBUF, KO1, KO2, ST_Q0, ST_Q123, VMQ3) do {                         \
    /* ---- q0: read B-lo cols + A rows 0-63; MFMA (i0-3, j0-1) ---- */                   \
    _Pragma("unroll") for (int j = 0; j < 2; ++j) {                                       \
        bf[j][0] = LDB(BUF, j, 0); bf[j][1] = LDB(BUF, j, 1); }                           \
    _Pragma("unroll") for (int i = 0; i < 4; ++i) {                                       \
        af[i][0] = LDA(BUF, i, 0); af[i][1] = LDA(BUF, i, 1); }                           \
    if (ST_Q0) STG_A(NBUF, 1, KO1);                                                       \
    BAR(); LGKM0();                                                                       \
    __builtin_amdgcn_s_setprio(1); MQ(0, 0); __builtin_amdgcn_s_setprio(0);               \
    BAR();                                                                                \
    /* ---- q1: read B-hi cols; MFMA (i0-3, j2-3) ---- */                                 \
    _Pragma("unroll") for (int j = 0; j < 2; ++j) {                                       \
        bf[2+j][0] = LDB(BUF, 2+j, 0); bf[2+j][1] = LDB(BUF, 2+j, 1); }                   \
    if (ST_Q123) STG_B(BUF, 0, KO2);                                                      \
    BAR(); LGKM0();                                                                       \
    __builtin_amdgcn_s_setprio(1); MQ(0, 2); __builtin_amdgcn_s_setprio(0);               \
    BAR();                                                                                \
    /* ---- q2: read A rows 64-127 (reuse af regs); MFMA (i4-7, j0-1) ---- */             \
    _Pragma("unroll") for (int i = 0; i < 4; ++i) {                                       \
        af[i][0] = LDA(BUF, 4+i, 0); af[i][1] = LDA(BUF, 4+i, 1); }                       \
    if (ST_Q123) STG_B(BUF, 1, KO2);                                                      \
    BAR(); LGKM0();                                                                       \
    __builtin_amdgcn_s_setprio(1); MQ(4, 0); __builtin_amdgcn_s_setprio(0);               \
    BAR();                                                                                \
    /* ---- q3: no reads; MFMA (i4-7, j2-3); counted vmcnt ---- */                        \
    if (ST_Q123) STG_A(BUF, 0, KO2);                                                      \
    BAR();                                                                                \
    __builtin_amdgcn_s_setprio(1); MQ(4, 2); __builtin_amdgcn_s_setprio(0);               \
    VMQ3;                                                                                 \
    BAR();                                                                                \
} while (0)

    // prologue: stream H[0..6] = B-lo(0),B-hi(0),A-lo(0),A-hi(0),B-lo(1),B-hi(1),A-lo(1)
    STG_B(0, 0, 0); STG_B(0, 1, 0); STG_A(0, 0, 0); STG_A(0, 1, 0);
    STG_B(1, 0, 128); STG_B(1, 1, 128); STG_A(1, 0, 128);
    VMC(6);  // 14 loads out, keep 6 -> tile 0's 8 loads complete
    BAR();

    // main loop: tiles 0..29 (15 iters x 2 tiles), steady-state vmcnt(6)
#pragma unroll 1
    for (int kt = 0; kt < 15; ++kt) {
        const int kb = kt * 256;  // T = 2*kt
        TILE_BODY(0, 1, kb + 128, kb + 256, 1, 1, VMC(6));
        TILE_BODY(1, 0, kb + 256, kb + 384, 1, 1, VMC(6));
    }
    // T=30: stage only A-hi(31) at q0; drain fully at q3
    TILE_BODY(0, 1, 3968, 0, 1, 0, VMC(0));
    // T=31: no staging, no vmcnt
    TILE_BODY(1, 0, 0, 0, 0, 0, ((void)0));

    const float ax = __uint_as_float(bits[0]);
    const float aw = __uint_as_float(bits[1]);
    const float s = (ax / 127.0f) * (aw / 127.0f);

    // C/D layout (16x16): col = lane&15, row = (lane>>4)*4 + reg
#pragma unroll
    for (int j = 0; j < 4; ++j) {
        const int col = n0 + wn * 64 + j * 16 + l15;
        const float bcol = bias[col];
#pragma unroll
        for (int i = 0; i < 8; ++i) {
            const int row0 = m0 + wm * 128 + i * 16 + l4 * 4;
#pragma unroll
            for (int r = 0; r < 4; ++r)
                out[(size_t)(row0 + r) * NDIM + col] = (float)acc[i][j][r] * s + bcol;
        }
    }
#undef GLL
#undef STG_A
#undef STG_B
#undef LDA
#undef LDB
#undef MQ
#undef BAR
#undef LGKM0
#undef VMC
#undef TILE_BODY
}

extern "C" void kernel_launch(void* const* d_in, const int* in_sizes, int n_in,
                              void* d_out, int out_size, void* d_ws, size_t ws_size,
                              hipStream_t stream) {
    const float* x    = (const float*)d_in[0];
    const float* w    = (const float*)d_in[1];
    const float* bias = (const float*)d_in[2];
    float* out = (float*)d_out;

    unsigned* bits = (unsigned*)d_ws;                 // [0]=absmax(x), [1]=absmax(w)
    signed char* xq = (signed char*)d_ws + 64;        // M*K int8 = 32 MB
    signed char* wq = xq + (size_t)MDIM * KDIM;       // N*K int8 = 16 MB

    hipMemsetAsync(d_ws, 0, 64, stream);

    absmax2_kernel<<<1536, 256, 0, stream>>>(x, w, bits);
    quant2_kernel<<<3072, 256, 0, stream>>>(x, w, bits, (int*)xq, (int*)wq);

    dim3 grid(NDIM / 256, MDIM / 256);
    gemm_i8<<<grid, 512, 0, stream>>>(xq, wq, bias, bits, out);
}

// Round 3
// 442.745 us; speedup vs baseline: 1.0879x; 1.0274x over previous
//
#include <hip/hip_runtime.h>
#include <stdint.h>

#define MDIM 8192
#define KDIM 4096
#define NDIM 4096

typedef int v4i __attribute__((ext_vector_type(4)));

// ---------------- absmax (per-tensor), x and w in ONE launch ----------------
__global__ __launch_bounds__(256) void absmax2_kernel(const float* __restrict__ x,
                                                      const float* __restrict__ w,
                                                      unsigned* __restrict__ bits) {
    __shared__ float smax[4];
    const float4* src;
    int idx, stride, n4;
    unsigned* slot;
    if (blockIdx.x < 1024) {
        src = (const float4*)x;
        idx = blockIdx.x * 256 + threadIdx.x;
        stride = 1024 * 256;
        n4 = MDIM * KDIM / 4;
        slot = bits;
    } else {
        src = (const float4*)w;
        idx = (blockIdx.x - 1024) * 256 + threadIdx.x;
        stride = 512 * 256;
        n4 = NDIM * KDIM / 4;
        slot = bits + 1;
    }
    float m = 0.0f;
    for (int i = idx; i < n4; i += 4 * stride) {
        float4 a = src[i];
        float4 b = src[i + stride];
        float4 c = src[i + 2 * stride];
        float4 d = src[i + 3 * stride];
        m = fmaxf(m, fmaxf(fmaxf(fabsf(a.x), fabsf(a.y)), fmaxf(fabsf(a.z), fabsf(a.w))));
        m = fmaxf(m, fmaxf(fmaxf(fabsf(b.x), fabsf(b.y)), fmaxf(fabsf(b.z), fabsf(b.w))));
        m = fmaxf(m, fmaxf(fmaxf(fabsf(c.x), fabsf(c.y)), fmaxf(fabsf(c.z), fabsf(c.w))));
        m = fmaxf(m, fmaxf(fmaxf(fabsf(d.x), fabsf(d.y)), fmaxf(fabsf(d.z), fabsf(d.w))));
    }
#pragma unroll
    for (int off = 32; off > 0; off >>= 1)
        m = fmaxf(m, __shfl_down(m, off, 64));
    if ((threadIdx.x & 63) == 0) smax[threadIdx.x >> 6] = m;
    __syncthreads();
    if (threadIdx.x == 0) {
        float bm = fmaxf(fmaxf(smax[0], smax[1]), fmaxf(smax[2], smax[3]));
        atomicMax(slot, __float_as_uint(bm));  // |x| >= 0: uint order == float order
    }
}

// ---------------- quantize fp32 -> int8, x and w in ONE launch ----------------
__global__ __launch_bounds__(256) void quant2_kernel(const float* __restrict__ x,
                                                     const float* __restrict__ w,
                                                     const unsigned* __restrict__ bits,
                                                     int* __restrict__ xq,
                                                     int* __restrict__ wq) {
    const float4* src;
    int idx, stride, n4;
    int* dst;
    float amax;
    if (blockIdx.x < 2048) {
        src = (const float4*)x;
        idx = blockIdx.x * 256 + threadIdx.x;
        stride = 2048 * 256;
        n4 = MDIM * KDIM / 4;
        dst = xq;
        amax = __uint_as_float(bits[0]);
    } else {
        src = (const float4*)w;
        idx = (blockIdx.x - 2048) * 256 + threadIdx.x;
        stride = 1024 * 256;
        n4 = NDIM * KDIM / 4;
        dst = wq;
        amax = __uint_as_float(bits[1]);
    }
    const float scale = (amax > 0.0f) ? (amax / 127.0f) : 1.0f;
    for (int i = idx; i < n4; i += 4 * stride) {
        float4 v[4];
        v[0] = src[i];
        v[1] = src[i + stride];
        v[2] = src[i + 2 * stride];
        v[3] = src[i + 3 * stride];
#pragma unroll
        for (int u = 0; u < 4; ++u) {
            int a = __float2int_rn(v[u].x / scale);  // IEEE div + rn == jnp.round(t/scale)
            int b = __float2int_rn(v[u].y / scale);
            int c = __float2int_rn(v[u].z / scale);
            int d = __float2int_rn(v[u].w / scale);
            a = min(127, max(-127, a));
            b = min(127, max(-127, b));
            c = min(127, max(-127, c));
            d = min(127, max(-127, d));
            dst[i + u * stride] =
                (a & 0xFF) | ((b & 0xFF) << 8) | ((c & 0xFF) << 16) | ((d & 0xFF) << 24);
        }
    }
}

// ---------------- int8 GEMM: C = Aq[M,K] . Wq[N,K]^T, dequant + bias ----------------
// 256x256 tile, 8 waves (2M x 4N), per-wave 128x64 out, dbuf LDS 128 KB.
// TAIL-ISSUED READ PIPELINE (1 barrier/phase): ds_reads for phase p+1 issue AFTER
// phase p's MFMA cluster, so the LDS drain overlaps other waves' MFMA windows.
// Phase order: q0=(i0-3,j01) q1=(i0-3,j23) q2=(i4-7,j23) q3=(i4-7,j01).
//   q1-tail: af <- afH (i4-7) [WAR vs q1 MFMA: compiler-ordered]
//   q3-tail: af <- afL(T+1), bf <- bf(T+1) from NBUF (boundary batch, 16 reads)
// Staging ledger (STG at phase head; each >=1 barrier after slot's last read):
//   q0: A-hi(T+1)->NBUF   [Ahi(T-1) reads done by BAR2(T-1)]
//   q1: B-lo(T+2)->BUF    [Blo(T) reads done by BAR0(T)]
//   q2: B-hi(T+2)->BUF    [Bhi(T) reads done by BAR0(T)]
//   q3: A-lo(T+2)->BUF    [Alo(T) reads (afL bound + afH wm=0) done by BAR2(T)]
// vmcnt(4) at q2 (post-MFMA): enter tile 6 outstanding, +2+2+2 = 12, drain 8 oldest
// = all of T+1 -> q3-tail boundary reads of NBUF legal after BAR2. Never 0 in loop.
// T1 XCD swizzle: lin -> (lin&7)*64 + lin>>3 (bijective, 512 = 8 x 64).
__global__ __launch_bounds__(512, 2) void gemm_i8(
    const signed char* __restrict__ Aq,
    const signed char* __restrict__ Wq,
    const float* __restrict__ bias,
    const unsigned* __restrict__ bits,
    float* __restrict__ out) {
    __shared__ __align__(16) signed char As[2 * 32768];  // [buf][256 rows][128 B]
    __shared__ __align__(16) signed char Bs[2 * 32768];

    const int tid  = threadIdx.x;
    const int lane = tid & 63;
    const int wave = tid >> 6;
    const int wm = wave >> 2;   // 0..1 -> M half (128 rows)
    const int wn = wave & 3;    // 0..3 -> N quarter (64 cols)
    const int l15 = lane & 15;
    const int l4  = lane >> 4;  // 0..3
    const int swz = l15 & 7;    // read-side swizzle = row&7

    // T1: XCD-aware bijective remap (8 XCDs x 64 tiles; by-chunked -> A L2-resident)
    const int lin = blockIdx.y * gridDim.x + blockIdx.x;
    const int nl  = (lin & 7) * 64 + (lin >> 3);
    const int m0 = (nl >> 4) * 256;
    const int n0 = (nl & 15) * 256;

    // staging: thread t covers granule (row = c*64 + t>>3, g = t&7) of chunk c;
    // source granule pre-swizzled g ^ (row&7) so linear LDS + swizzled read match
    const int srow = tid >> 3;                         // 0..63 within chunk
    const int scol = ((tid & 7) ^ (srow & 7)) << 4;    // pre-swizzled source byte col
    const signed char* aSrc[4];
    const signed char* bSrc[4];
#pragma unroll
    for (int c = 0; c < 4; ++c) {
        aSrc[c] = Aq + (size_t)(m0 + c * 64 + srow) * KDIM + scol;
        bSrc[c] = Wq + (size_t)(n0 + c * 64 + srow) * KDIM + scol;
    }
    const int ldst = tid * 16;

    v4i acc[8][4] = {};
    v4i af[4][2], bf[4][2];

#define GLL(SRC, DST) __builtin_amdgcn_global_load_lds(                                   \
        (const __attribute__((address_space(1))) void*)(SRC),                             \
        (__attribute__((address_space(3))) void*)(DST), 16, 0, 0)

#define STG_A(BUF, h, KO) do {                                                            \
    GLL(aSrc[(h)*2 + 0] + (KO), As + (BUF)*32768 + (h)*16384 + 0*8192 + ldst);            \
    GLL(aSrc[(h)*2 + 1] + (KO), As + (BUF)*32768 + (h)*16384 + 1*8192 + ldst);            \
} while (0)
#define STG_B(BUF, h, KO) do {                                                            \
    GLL(bSrc[(h)*2 + 0] + (KO), Bs + (BUF)*32768 + (h)*16384 + 0*8192 + ldst);            \
    GLL(bSrc[(h)*2 + 1] + (KO), Bs + (BUF)*32768 + (h)*16384 + 1*8192 + ldst);            \
} while (0)

#define LDA(BUF, i, kk) (*(const v4i*)(As + (BUF)*32768 +                                 \
        (wm*128 + (i)*16 + l15)*128 + (((((kk)<<2) | l4) ^ swz) << 4)))
#define LDB(BUF, j, kk) (*(const v4i*)(Bs + (BUF)*32768 +                                 \
        (wn*64 + (j)*16 + l15)*128 + (((((kk)<<2) | l4) ^ swz) << 4)))

#define MQ(I0, J0) do {                                                                   \
    _Pragma("unroll") for (int kk = 0; kk < 2; ++kk)                                      \
    _Pragma("unroll") for (int i = 0; i < 4; ++i)                                         \
    _Pragma("unroll") for (int j = 0; j < 2; ++j)                                         \
        acc[(I0)+i][(J0)+j] = __builtin_amdgcn_mfma_i32_16x16x64_i8(                      \
            af[i][kk], bf[(J0)+j][kk], acc[(I0)+i][(J0)+j], 0, 0, 0);                     \
} while (0)

#define BAR()   do { __builtin_amdgcn_s_barrier(); asm volatile("" ::: "memory"); } while (0)
#define LGKM0() asm volatile("s_waitcnt lgkmcnt(0)" ::: "memory")
#define VMC(n)  asm volatile("s_waitcnt vmcnt(" #n ")" ::: "memory")

#define RD_AFH(BUF) do {                                                                  \
    _Pragma("unroll") for (int i = 0; i < 4; ++i) {                                       \
        af[i][0] = LDA(BUF, 4 + i, 0); af[i][1] = LDA(BUF, 4 + i, 1); }                   \
} while (0)
#define RD_BOUND(BUF) do {                                                                \
    _Pragma("unroll") for (int j = 0; j < 4; ++j) {                                       \
        bf[j][0] = LDB(BUF, j, 0); bf[j][1] = LDB(BUF, j, 1); }                           \
    _Pragma("unroll") for (int i = 0; i < 4; ++i) {                                       \
        af[i][0] = LDA(BUF, i, 0); af[i][1] = LDA(BUF, i, 1); }                           \
} while (0)

// One K-tile. Entering: af=afL(T), bf=bf(T) loaded (boundary), 6 gll outstanding.
#define TILE_BODY(BUF, NBUF, KO1, KO2, ST0, ST123, VMQ2, DO_BOUND) do {                   \
    /* q0: MFMA (i0-3, j0-1) */                                                           \
    if (ST0) STG_A(NBUF, 1, KO1);                                                         \
    LGKM0();                                                                              \
    __builtin_amdgcn_s_setprio(1); MQ(0, 0); __builtin_amdgcn_s_setprio(0);               \
    BAR();                                                                                \
    /* q1: MFMA (i0-3, j2-3); tail: af <- afH */                                          \
    if (ST123) STG_B(BUF, 0, KO2);                                                        \
    __builtin_amdgcn_s_setprio(1); MQ(0, 2); __builtin_amdgcn_s_setprio(0);               \
    RD_AFH(BUF);                                                                          \
    BAR();                                                                                \
    /* q2: MFMA (i4-7, j2-3); post-MFMA counted vmcnt */                                  \
    if (ST123) STG_B(BUF, 1, KO2);                                                        \
    LGKM0();                                                                              \
    __builtin_amdgcn_s_setprio(1); MQ(4, 2); __builtin_amdgcn_s_setprio(0);               \
    VMQ2;                                                                                 \
    BAR();                                                                                \
    /* q3: MFMA (i4-7, j0-1); tail: boundary reads for T+1 from NBUF */                   \
    if (ST123) STG_A(BUF, 0, KO2);                                                        \
    __builtin_amdgcn_s_setprio(1); MQ(4, 0); __builtin_amdgcn_s_setprio(0);               \
    if (DO_BOUND) RD_BOUND(NBUF);                                                         \
    BAR();                                                                                \
} while (0)

    // prologue: tile0 (8 loads) + Blo,Bhi,Alo of tile1 (6 loads); Ahi(1) staged at q0(0)
    STG_B(0, 0, 0); STG_B(0, 1, 0); STG_A(0, 0, 0); STG_A(0, 1, 0);
    STG_B(1, 0, 128); STG_B(1, 1, 128); STG_A(1, 0, 128);
    VMC(6);  // 14 out, keep 6 -> tile 0 complete
    BAR();
    RD_BOUND(0);  // boundary regs for tile 0

#pragma unroll 1
    for (int kt = 0; kt < 15; ++kt) {
        const int kb = kt * 256;  // T = 2*kt
        TILE_BODY(0, 1, kb + 128, kb + 256, 1, 1, VMC(4), 1);
        TILE_BODY(1, 0, kb + 256, kb + 384, 1, 1, VMC(4), 1);
    }
    // tile 30: stage only Ahi(31); outstanding 6+2=8 -> drain all at q2
    TILE_BODY(0, 1, 3968, 0, 1, 0, VMC(0), 1);
    // tile 31: no staging, no vmcnt, no boundary
    TILE_BODY(1, 0, 0, 0, 0, 0, ((void)0), 0);

    const float ax = __uint_as_float(bits[0]);
    const float aw = __uint_as_float(bits[1]);
    const float s = (ax / 127.0f) * (aw / 127.0f);

    // C/D layout (16x16): col = lane&15, row = (lane>>4)*4 + reg
#pragma unroll
    for (int j = 0; j < 4; ++j) {
        const int col = n0 + wn * 64 + j * 16 + l15;
        const float bcol = bias[col];
#pragma unroll
        for (int i = 0; i < 8; ++i) {
            const int row0 = m0 + wm * 128 + i * 16 + l4 * 4;
#pragma unroll
            for (int r = 0; r < 4; ++r)
                out[(size_t)(row0 + r) * NDIM + col] = (float)acc[i][j][r] * s + bcol;
        }
    }
#undef GLL
#undef STG_A
#undef STG_B
#undef LDA
#undef LDB
#undef MQ
#undef BAR
#undef LGKM0
#undef VMC
#undef RD_AFH
#undef RD_BOUND
#undef TILE_BODY
}

extern "C" void kernel_launch(void* const* d_in, const int* in_sizes, int n_in,
                              void* d_out, int out_size, void* d_ws, size_t ws_size,
                              hipStream_t stream) {
    const float* x    = (const float*)d_in[0];
    const float* w    = (const float*)d_in[1];
    const float* bias = (const float*)d_in[2];
    float* out = (float*)d_out;

    unsigned* bits = (unsigned*)d_ws;                 // [0]=absmax(x), [1]=absmax(w)
    signed char* xq = (signed char*)d_ws + 64;        // M*K int8 = 32 MB
    signed char* wq = xq + (size_t)MDIM * KDIM;       // N*K int8 = 16 MB

    hipMemsetAsync(d_ws, 0, 64, stream);

    absmax2_kernel<<<1536, 256, 0, stream>>>(x, w, bits);
    quant2_kernel<<<3072, 256, 0, stream>>>(x, w, bits, (int*)xq, (int*)wq);

    dim3 grid(NDIM / 256, MDIM / 256);
    gemm_i8<<<grid, 512, 0, stream>>>(xq, wq, bias, bits, out);
}